// Round 5
// baseline (2506.530 us; speedup 1.0000x reference)
//
#include <hip/hip_runtime.h>
#include <hip/hip_bf16.h>
#include <stdint.h>
#include <math.h>

#define BATCH 16384
#define DIN   784
#define HID   4096
#define DOUT  10
#define KW    128            // HID/32 words per row
#define CAP   1048576
#define BN_EPS 1e-5
#define TAU   0.05f          // |h_mfma - h_chain| worst ~1e-2; 5x margin

// ---------------- workspace layout (bytes) ----------------
constexpr size_t SZ_BITS   = (size_t)BATCH * KW * 4;     // 8 MB
constexpr size_t OFF_BITS1 = 0;
constexpr size_t OFF_BITS2 = OFF_BITS1 + SZ_BITS;
constexpr size_t OFF_W2B   = OFF_BITS2 + SZ_BITS;
constexpr size_t OFF_W3B   = OFF_W2B + (size_t)HID * KW * 4;
constexpr size_t OFF_W4B   = OFF_W3B + (size_t)HID * KW * 4;
constexpr size_t OFF_CNT   = OFF_W4B + 8192;
constexpr size_t OFF_LIST  = OFF_CNT + 16;               // 4 MB list

typedef __attribute__((ext_vector_type(8))) short frag8;   // 8 bf16 (4 VGPRs)
typedef __attribute__((ext_vector_type(4))) float f32x4;   // MFMA accum

__device__ __forceinline__ unsigned short f2bf_bits(float x) {
  __hip_bfloat16 h = __float2bfloat16(x);   // RNE
  return *reinterpret_cast<unsigned short*>(&h);
}
__device__ __forceinline__ float bf2f(unsigned short b) {
  union { unsigned int u; float f; } c;
  c.u = ((unsigned int)b) << 16;
  return c.f;
}

__global__ void zero_cnt_kernel(int* cnt) {
  if (threadIdx.x == 0) *cnt = 0;
}

// binarize a row-major fp32 matrix into bitmask words (bit e of word t = sign)
__global__ __launch_bounds__(256) void binarize_kernel(
    const float* __restrict__ w, uint32_t* __restrict__ bits, int nwords) {
  int t = blockIdx.x * 256 + threadIdx.x;
  if (t >= nwords) return;
  const float* p = w + (size_t)t * 32;
  uint32_t word = 0;
#pragma unroll
  for (int q = 0; q < 8; ++q) {
    float4 v = *(const float4*)(p + q * 4);
    word |= (uint32_t)(v.x >= 0.f) << (4 * q + 0);
    word |= (uint32_t)(v.y >= 0.f) << (4 * q + 1);
    word |= (uint32_t)(v.z >= 0.f) << (4 * q + 2);
    word |= (uint32_t)(v.w >= 0.f) << (4 * q + 3);
  }
  bits[t] = word;
}

// Layer 1 via bf16 MFMA, 2-term split of X (W-signs are exact in bf16).
// 128x128 tile, BK=32, 4 waves each computing 64x64 (4x4 frags of 16x16x32).
// Epilogue: BN sign; |h+b| within TAU -> fixup list (recomputed with the
// reference's sequential f32 FMA chain by fixup_chain_kernel).
__global__ __launch_bounds__(256) void gemm1_mfma_kernel(
    const float* __restrict__ X, const float* __restrict__ W,
    const float* __restrict__ Bv, const float* __restrict__ Gv,
    const float* __restrict__ BEv, const float* __restrict__ Mv,
    const float* __restrict__ Vv,
    uint32_t* __restrict__ bits_out, int* __restrict__ cnt,
    uint32_t* __restrict__ list) {
  // LDS row stride 40 bf16 (80 B): rows hit banks 20r%32 -> 2-way only (free)
  __shared__ short Ah[128 * 40];          // 10 KB  X-hi tile [m][k]
  __shared__ short Al[128 * 40];          // 10 KB  X-lo tile
  __shared__ short Bt[128 * 40];          // 10 KB  sign(W) tile [n][k]
  __shared__ unsigned short PW16[128 * 8]; // 2 KB  packed sign bits

  const int tid = threadIdx.x;
  const int bid = blockIdx.x;
  const int grp = bid >> 10;
  const int rem = bid & 1023;
  const int cb  = (grp << 3) + (rem & 7);   // 0..31
  const int rb  = rem >> 3;                 // 0..127
  const int m0 = rb * 128, n0 = cb * 128;

  const int lane = tid & 63;
  const int wm = (tid >> 6) & 1;      // wave row block (64)
  const int wn = tid >> 7;            // wave col block (64)
  const int l15 = lane & 15;
  const int l4  = lane >> 4;          // 0..3

  f32x4 acc[4][4];
#pragma unroll
  for (int i = 0; i < 4; ++i)
#pragma unroll
    for (int j = 0; j < 4; ++j) acc[i][j] = (f32x4){0.f, 0.f, 0.f, 0.f};

  // staging: thread -> row tid>>1 (0..127), k-half (tid&1)*16
  const int srow = tid >> 1;
  const int skb  = (tid & 1) * 16;
  const float* xp = X + (size_t)(m0 + srow) * DIN;
  const float* wp = W + (size_t)(n0 + srow) * DIN;

  for (int k0 = 0; k0 < 800; k0 += 32) {   // 25 slabs; last half zero-padded
    float xv[16], wv[16];
    const int kg = k0 + skb;
    if (kg < DIN) {   // kg in {0..768} here; kg+16 <= 784 always (784=49*16)
#pragma unroll
      for (int q = 0; q < 4; ++q) {
        *(float4*)&xv[q * 4] = *(const float4*)(xp + kg + q * 4);
        *(float4*)&wv[q * 4] = *(const float4*)(wp + kg + q * 4);
      }
    } else {
#pragma unroll
      for (int e = 0; e < 16; ++e) { xv[e] = 0.f; wv[e] = 1.f; }
    }
    unsigned int ah[8], al[8], bt[8];
#pragma unroll
    for (int q = 0; q < 8; ++q) {
      unsigned short h0 = f2bf_bits(xv[2 * q]);
      unsigned short h1 = f2bf_bits(xv[2 * q + 1]);
      unsigned short l0 = f2bf_bits(xv[2 * q] - bf2f(h0));
      unsigned short l1 = f2bf_bits(xv[2 * q + 1] - bf2f(h1));
      unsigned short s0 = (wv[2 * q] >= 0.f) ? 0x3F80u : 0xBF80u;
      unsigned short s1 = (wv[2 * q + 1] >= 0.f) ? 0x3F80u : 0xBF80u;
      ah[q] = (unsigned int)h0 | ((unsigned int)h1 << 16);
      al[q] = (unsigned int)l0 | ((unsigned int)l1 << 16);
      bt[q] = (unsigned int)s0 | ((unsigned int)s1 << 16);
    }
    __syncthreads();
    {
      const int o = srow * 40 + skb;   // short index; byte addr 16B-aligned
      *(uint4*)&Ah[o]     = *(uint4*)&ah[0];
      *(uint4*)&Ah[o + 8] = *(uint4*)&ah[4];
      *(uint4*)&Al[o]     = *(uint4*)&al[0];
      *(uint4*)&Al[o + 8] = *(uint4*)&al[4];
      *(uint4*)&Bt[o]     = *(uint4*)&bt[0];
      *(uint4*)&Bt[o + 8] = *(uint4*)&bt[4];
    }
    __syncthreads();

    frag8 bf[4], af_h[4], af_l[4];
#pragma unroll
    for (int f = 0; f < 4; ++f) {
      bf[f]   = *(const frag8*)&Bt[(wn * 64 + f * 16 + l15) * 40 + l4 * 8];
      af_h[f] = *(const frag8*)&Ah[(wm * 64 + f * 16 + l15) * 40 + l4 * 8];
      af_l[f] = *(const frag8*)&Al[(wm * 64 + f * 16 + l15) * 40 + l4 * 8];
    }
#pragma unroll
    for (int fm = 0; fm < 4; ++fm)
#pragma unroll
      for (int fn = 0; fn < 4; ++fn) {
        acc[fm][fn] = __builtin_amdgcn_mfma_f32_16x16x32_bf16(
            af_h[fm], bf[fn], acc[fm][fn], 0, 0, 0);
        acc[fm][fn] = __builtin_amdgcn_mfma_f32_16x16x32_bf16(
            af_l[fm], bf[fn], acc[fm][fn], 0, 0, 0);
      }
  }

  // ---- epilogue: BN sign + borderline flag + ballot pack ----
#pragma unroll
  for (int fn = 0; fn < 4; ++fn) {
    const int gj = n0 + wn * 64 + fn * 16 + l15;
    const float  bj = Bv[gj];
    const double scale = (double)Gv[gj] / sqrt((double)Vv[gj] + BN_EPS);
    const double mj = (double)Mv[gj], bej = (double)BEv[gj];
    const double thr = (double)TAU * fabs(scale);
#pragma unroll
    for (int fm = 0; fm < 4; ++fm) {
#pragma unroll
      for (int r = 0; r < 4; ++r) {
        const int row_l = wm * 64 + fm * 16 + l4 * 4 + r;
        float hb = acc[fm][fn][r] + bj;            // f32, matches chain epilogue
        double bnd = ((double)hb - mj) * scale + bej;
        unsigned int bit = (bnd >= 0.0) ? 1u : 0u;
        unsigned long long mask = __ballot(bit);
        if (l15 == 0)
          PW16[row_l * 8 + (wn * 4 + fn)] =
              (unsigned short)(mask >> (l4 * 16));
        if (fabs(bnd) < thr) {
          int pos = atomicAdd(cnt, 1);
          if (pos < CAP)
            list[pos] = (uint32_t)((m0 + row_l) * HID + gj);
        }
      }
    }
  }
  __syncthreads();
  for (int t = tid; t < 512; t += 256) {
    int row = t >> 2, wc = t & 3;
    uint32_t word = (uint32_t)PW16[row * 8 + wc * 2] |
                    ((uint32_t)PW16[row * 8 + wc * 2 + 1] << 16);
    bits_out[(size_t)(m0 + row) * KW + (n0 >> 5) + wc] = word;
  }
}

// Recompute flagged layer-1 elements with the reference's EXACT semantics:
// sequential ascending-k single f32 FMA chain, then h + b in f32, then BN.
__global__ __launch_bounds__(256) void fixup_chain_kernel(
    const float* __restrict__ X, const float* __restrict__ W,
    const float* __restrict__ Bv, const float* __restrict__ Gv,
    const float* __restrict__ BEv, const float* __restrict__ Mv,
    const float* __restrict__ Vv,
    uint32_t* __restrict__ bits1, const int* __restrict__ cnt,
    const uint32_t* __restrict__ list) {
  int n = *cnt;
  if (n > CAP) n = CAP;
  for (int idx = blockIdx.x * 256 + threadIdx.x; idx < n;
       idx += gridDim.x * 256) {
    uint32_t code = list[idx];
    int i = code >> 12;
    int j = code & (HID - 1);
    const float* xr = X + (size_t)i * DIN;
    const float* wr = W + (size_t)j * DIN;
    float h = 0.f;
    for (int k = 0; k < DIN; k += 4) {     // strictly ascending k
      float4 xv = *(const float4*)(xr + k);
      float4 wv = *(const float4*)(wr + k);
      h = fmaf(xv.x, (wv.x >= 0.f) ? 1.f : -1.f, h);
      h = fmaf(xv.y, (wv.y >= 0.f) ? 1.f : -1.f, h);
      h = fmaf(xv.z, (wv.z >= 0.f) ? 1.f : -1.f, h);
      h = fmaf(xv.w, (wv.w >= 0.f) ? 1.f : -1.f, h);
    }
    float hb = h + Bv[j];
    double scale = (double)Gv[j] / sqrt((double)Vv[j] + BN_EPS);
    double bnd = ((double)hb - (double)Mv[j]) * scale + (double)BEv[j];
    uint32_t bit = (bnd >= 0.0) ? 1u : 0u;
    uint32_t* wpw = &bits1[(size_t)i * KW + (j >> 5)];
    uint32_t cur = (*wpw >> (j & 31)) & 1u;
    if (cur != bit) atomicXor(wpw, 1u << (j & 31));
  }
}

// Layers 2/3: +-1 x +-1 GEMM via XOR+popcount (exact). BN -> sign bits out.
__global__ __launch_bounds__(256) void bitgemm_kernel(
    const uint32_t* __restrict__ Abits, const uint32_t* __restrict__ Wbits,
    const float* __restrict__ Bv, const float* __restrict__ Gv,
    const float* __restrict__ BEv, const float* __restrict__ Mv,
    const float* __restrict__ Vv, uint32_t* __restrict__ bits_out) {
  __shared__ uint32_t As[16 * 128];
  __shared__ uint32_t Bs[16 * 128];
  __shared__ unsigned int PW[128 * 4];

  const int tid = threadIdx.x;
  const int cb = blockIdx.x & 31, rb = blockIdx.x >> 5;
  const int m0 = rb * 128, n0 = cb * 128;
  const int tx = tid & 15, ty = tid >> 4;

  int acc[8][8];
#pragma unroll
  for (int r = 0; r < 8; ++r)
#pragma unroll
    for (int c = 0; c < 8; ++c) acc[r][c] = 0;

  const int sr = tid >> 1;
  const int sk = (tid & 1) * 8;
  const uint32_t* arow = Abits + (size_t)(m0 + sr) * KW + sk;
  const uint32_t* wrow = Wbits + (size_t)(n0 + sr) * KW + sk;

  for (int w0 = 0; w0 < KW; w0 += 16) {
    uint4 a0 = *(const uint4*)(arow + w0);
    uint4 a1 = *(const uint4*)(arow + w0 + 4);
    uint4 b0 = *(const uint4*)(wrow + w0);
    uint4 b1 = *(const uint4*)(wrow + w0 + 4);
    __syncthreads();
    As[(sk + 0) * 128 + sr] = a0.x;  As[(sk + 1) * 128 + sr] = a0.y;
    As[(sk + 2) * 128 + sr] = a0.z;  As[(sk + 3) * 128 + sr] = a0.w;
    As[(sk + 4) * 128 + sr] = a1.x;  As[(sk + 5) * 128 + sr] = a1.y;
    As[(sk + 6) * 128 + sr] = a1.z;  As[(sk + 7) * 128 + sr] = a1.w;
    Bs[(sk + 0) * 128 + sr] = b0.x;  Bs[(sk + 1) * 128 + sr] = b0.y;
    Bs[(sk + 2) * 128 + sr] = b0.z;  Bs[(sk + 3) * 128 + sr] = b0.w;
    Bs[(sk + 4) * 128 + sr] = b1.x;  Bs[(sk + 5) * 128 + sr] = b1.y;
    Bs[(sk + 6) * 128 + sr] = b1.z;  Bs[(sk + 7) * 128 + sr] = b1.w;
    __syncthreads();
#pragma unroll
    for (int kk = 0; kk < 16; ++kk) {
      uint32_t a[8], b[8];
      *(uint4*)&a[0] = *(const uint4*)&As[kk * 128 + ty * 8];
      *(uint4*)&a[4] = *(const uint4*)&As[kk * 128 + ty * 8 + 4];
      *(uint4*)&b[0] = *(const uint4*)&Bs[kk * 128 + tx * 8];
      *(uint4*)&b[4] = *(const uint4*)&Bs[kk * 128 + tx * 8 + 4];
#pragma unroll
      for (int r = 0; r < 8; ++r)
#pragma unroll
        for (int c = 0; c < 8; ++c)
          acc[r][c] += __popc(a[r] ^ b[c]);
    }
  }

  uint32_t bm[8];
#pragma unroll
  for (int r = 0; r < 8; ++r) bm[r] = 0;
  for (int c = 0; c < 8; ++c) {
    const int j = n0 + tx * 8 + c;
    const double scale = (double)Gv[j] / sqrt((double)Vv[j] + BN_EPS);
    const double mj = (double)Mv[j], bej = (double)BEv[j], bj = (double)Bv[j];
#pragma unroll
    for (int r = 0; r < 8; ++r) {
      double h = (double)(HID - 2 * acc[r][c]) + bj;   // exact integer dot
      double bnd = (h - mj) * scale + bej;
      bm[r] |= (uint32_t)(bnd >= 0.0) << c;
    }
  }
  for (int t = tid; t < 512; t += 256) PW[t] = 0u;
  __syncthreads();
#pragma unroll
  for (int r = 0; r < 8; ++r)
    atomicOr(&PW[(ty * 8 + r) * 4 + (tx >> 2)], bm[r] << (8 * (tx & 3)));
  __syncthreads();
  for (int w = tid; w < 512; w += 256) {
    int row = w >> 2, wc = w & 3;
    bits_out[(size_t)(m0 + row) * KW + (n0 >> 5) + wc] = PW[row * 4 + wc];
  }
}

// Layer 4 (10 outputs) + log_softmax. One wave per batch row.
__global__ __launch_bounds__(256) void final_kernel(
    const uint32_t* __restrict__ xbits, const uint32_t* __restrict__ w4b,
    const float* __restrict__ b4, float* __restrict__ out) {
  __shared__ uint32_t Ws[DOUT * KW];   // 5 KB
  const int tid = threadIdx.x;
  for (int t = tid; t < DOUT * KW; t += 256) Ws[t] = w4b[t];
  __syncthreads();
  const int lane = tid & 63;
  const int i = blockIdx.x * 4 + (tid >> 6);
  const uint32_t x0 = xbits[(size_t)i * KW + lane];
  const uint32_t x1 = xbits[(size_t)i * KW + 64 + lane];
  int cnt[DOUT];
#pragma unroll
  for (int j = 0; j < DOUT; ++j)
    cnt[j] = __popc(x0 ^ Ws[j * KW + lane]) + __popc(x1 ^ Ws[j * KW + 64 + lane]);
#pragma unroll
  for (int j = 0; j < DOUT; ++j)
#pragma unroll
    for (int off = 32; off; off >>= 1) cnt[j] += __shfl_xor(cnt[j], off);
  double logit[DOUT];
  double mx = -1e300;
#pragma unroll
  for (int j = 0; j < DOUT; ++j) {
    logit[j] = (double)(HID - 2 * cnt[j]) + (double)b4[j];
    mx = fmax(mx, logit[j]);
  }
  double s = 0.0;
#pragma unroll
  for (int j = 0; j < DOUT; ++j) s += exp(logit[j] - mx);
  double lse = log(s) + mx;
  if (lane < DOUT)
    out[(size_t)i * DOUT + lane] = (float)(logit[lane] - lse);
}

extern "C" void kernel_launch(void* const* d_in, const int* in_sizes, int n_in,
                              void* d_out, int out_size, void* d_ws, size_t ws_size,
                              hipStream_t stream) {
  const float* x   = (const float*)d_in[0];
  const float* w1  = (const float*)d_in[1];
  const float* b1  = (const float*)d_in[2];
  const float* g1  = (const float*)d_in[3];
  const float* be1 = (const float*)d_in[4];
  const float* m1  = (const float*)d_in[5];
  const float* v1  = (const float*)d_in[6];
  const float* w2  = (const float*)d_in[7];
  const float* b2  = (const float*)d_in[8];
  const float* g2  = (const float*)d_in[9];
  const float* be2 = (const float*)d_in[10];
  const float* m2  = (const float*)d_in[11];
  const float* v2  = (const float*)d_in[12];
  const float* w3  = (const float*)d_in[13];
  const float* b3  = (const float*)d_in[14];
  const float* g3  = (const float*)d_in[15];
  const float* be3 = (const float*)d_in[16];
  const float* v3  = (const float*)d_in[18];
  const float* m3  = (const float*)d_in[17];
  const float* w4  = (const float*)d_in[19];
  const float* b4  = (const float*)d_in[20];

  char* ws = (char*)d_ws;
  uint32_t* bits1 = (uint32_t*)(ws + OFF_BITS1);
  uint32_t* bits2 = (uint32_t*)(ws + OFF_BITS2);
  uint32_t* w2b   = (uint32_t*)(ws + OFF_W2B);
  uint32_t* w3b   = (uint32_t*)(ws + OFF_W3B);
  uint32_t* w4b   = (uint32_t*)(ws + OFF_W4B);
  int*      cnt   = (int*)(ws + OFF_CNT);
  uint32_t* list  = (uint32_t*)(ws + OFF_LIST);
  float*    out   = (float*)d_out;

  zero_cnt_kernel<<<1, 64, 0, stream>>>(cnt);
  binarize_kernel<<<(HID * KW + 255) / 256, 256, 0, stream>>>(w2, w2b, HID * KW);
  binarize_kernel<<<(HID * KW + 255) / 256, 256, 0, stream>>>(w3, w3b, HID * KW);
  binarize_kernel<<<(DOUT * KW + 255) / 256, 256, 0, stream>>>(w4, w4b, DOUT * KW);

  gemm1_mfma_kernel<<<(BATCH / 128) * (HID / 128), 256, 0, stream>>>(
      x, w1, b1, g1, be1, m1, v1, bits1, cnt, list);
  fixup_chain_kernel<<<512, 256, 0, stream>>>(
      x, w1, b1, g1, be1, m1, v1, bits1, cnt, list);

  bitgemm_kernel<<<(BATCH / 128) * (HID / 128), 256, 0, stream>>>(
      bits1, w2b, b2, g2, be2, m2, v2, bits2);
  bitgemm_kernel<<<(BATCH / 128) * (HID / 128), 256, 0, stream>>>(
      bits2, w3b, b3, g3, be3, m3, v3, bits1);

  final_kernel<<<BATCH / 4, 256, 0, stream>>>(bits1, w4b, b4, out);
}

// Round 6
// 2501.819 us; speedup vs baseline: 1.0019x; 1.0019x over previous
//
#include <hip/hip_runtime.h>
#include <hip/hip_bf16.h>
#include <stdint.h>
#include <math.h>

#define BATCH 16384
#define DIN   784
#define HID   4096
#define DOUT  10
#define KW    128            // HID/32 words per row
#define KP    1600           // padded split-K: hi[0,784) lo[784,1568) pad[1568,1600)
#define CAP   1048576
#define BN_EPS 1e-5
#define TAU   0.05f          // |h_mfma - h_chain| worst ~1e-2; 5x margin (verified R5)

// ---------------- workspace layout (bytes) ----------------
constexpr size_t SZ_BITS   = (size_t)BATCH * KW * 4;     // 8 MB
constexpr size_t OFF_BITS1 = 0;
constexpr size_t OFF_BITS2 = OFF_BITS1 + SZ_BITS;
constexpr size_t OFF_W2B   = OFF_BITS2 + SZ_BITS;
constexpr size_t OFF_W3B   = OFF_W2B + (size_t)HID * KW * 4;
constexpr size_t OFF_W4B   = OFF_W3B + (size_t)HID * KW * 4;
constexpr size_t OFF_CNT   = OFF_W4B + 8192;
constexpr size_t OFF_LIST  = OFF_CNT + 256;
constexpr size_t OFF_XHL   = (OFF_LIST + (size_t)CAP * 4 + 255) & ~(size_t)255;
constexpr size_t OFF_WSD   = OFF_XHL + (size_t)BATCH * KP * 2;   // 52.4 MB
// Wsd: 4096*1600*2 = 13.1 MB; total ~90 MB

typedef __attribute__((ext_vector_type(8))) short frag8;   // 8 bf16 (4 VGPRs)
typedef __attribute__((ext_vector_type(4))) float f32x4;   // MFMA accum

typedef const __attribute__((address_space(1))) uint32_t guint;
typedef __attribute__((address_space(3))) uint32_t luint;

__device__ __forceinline__ void load16_to_lds(const void* g, void* l) {
  __builtin_amdgcn_global_load_lds((guint*)g, (luint*)l, 16, 0, 0);
}

__device__ __forceinline__ unsigned short f2bf_bits(float x) {
  __hip_bfloat16 h = __float2bfloat16(x);   // RNE
  return *reinterpret_cast<unsigned short*>(&h);
}
__device__ __forceinline__ float bf2f(unsigned short b) {
  union { unsigned int u; float f; } c;
  c.u = ((unsigned int)b) << 16;
  return c.f;
}

__global__ void zero_cnt_kernel(int* cnt) {
  if (threadIdx.x == 0) *cnt = 0;
}

// binarize a row-major fp32 matrix into bitmask words
__global__ __launch_bounds__(256) void binarize_kernel(
    const float* __restrict__ w, uint32_t* __restrict__ bits, int nwords) {
  int t = blockIdx.x * 256 + threadIdx.x;
  if (t >= nwords) return;
  const float* p = w + (size_t)t * 32;
  uint32_t word = 0;
#pragma unroll
  for (int q = 0; q < 8; ++q) {
    float4 v = *(const float4*)(p + q * 4);
    word |= (uint32_t)(v.x >= 0.f) << (4 * q + 0);
    word |= (uint32_t)(v.y >= 0.f) << (4 * q + 1);
    word |= (uint32_t)(v.z >= 0.f) << (4 * q + 2);
    word |= (uint32_t)(v.w >= 0.f) << (4 * q + 3);
  }
  bits[t] = word;
}

// X -> bf16 hi/lo split, row layout [hi 0..783 | lo 784..1567 | zero pad ..1599]
__global__ __launch_bounds__(256) void convert_x_kernel(
    const float* __restrict__ X, short* __restrict__ Xhl) {
  int idx = blockIdx.x * 256 + threadIdx.x;      // BATCH*50 = 819200 exact
  int row = idx / 50, kq = idx - row * 50;
  short* orow = Xhl + (size_t)row * KP;
  if (kq < 49) {
    const float* p = X + (size_t)row * DIN + kq * 16;
    short hi[16], lo[16];
#pragma unroll
    for (int q = 0; q < 4; ++q) {
      float4 v = *(const float4*)(p + q * 4);
      float vv[4] = {v.x, v.y, v.z, v.w};
#pragma unroll
      for (int e = 0; e < 4; ++e) {
        unsigned short h = f2bf_bits(vv[e]);
        hi[q * 4 + e] = (short)h;
        lo[q * 4 + e] = (short)f2bf_bits(vv[e] - bf2f(h));
      }
    }
    *(uint4*)(orow + kq * 16)           = *(uint4*)&hi[0];
    *(uint4*)(orow + kq * 16 + 8)       = *(uint4*)&hi[8];
    *(uint4*)(orow + 784 + kq * 16)     = *(uint4*)&lo[0];
    *(uint4*)(orow + 784 + kq * 16 + 8) = *(uint4*)&lo[8];
  } else {
    uint4 z = {0, 0, 0, 0};
#pragma unroll
    for (int q = 0; q < 4; ++q) *(uint4*)(orow + 1568 + q * 8) = z;
  }
}

// W1 -> sign(+-1) bf16 duplicated in both K-halves, zero pad
__global__ __launch_bounds__(256) void convert_w_kernel(
    const float* __restrict__ W, short* __restrict__ Wsd) {
  int idx = blockIdx.x * 256 + threadIdx.x;      // HID*50 = 204800 exact
  int row = idx / 50, kq = idx - row * 50;
  short* orow = Wsd + (size_t)row * KP;
  if (kq < 49) {
    const float* p = W + (size_t)row * DIN + kq * 16;
    short s[16];
#pragma unroll
    for (int q = 0; q < 4; ++q) {
      float4 v = *(const float4*)(p + q * 4);
      s[q * 4 + 0] = (short)((v.x >= 0.f) ? 0x3F80 : 0xBF80);
      s[q * 4 + 1] = (short)((v.y >= 0.f) ? 0x3F80 : 0xBF80);
      s[q * 4 + 2] = (short)((v.z >= 0.f) ? 0x3F80 : 0xBF80);
      s[q * 4 + 3] = (short)((v.w >= 0.f) ? 0x3F80 : 0xBF80);
    }
    *(uint4*)(orow + kq * 16)           = *(uint4*)&s[0];
    *(uint4*)(orow + kq * 16 + 8)       = *(uint4*)&s[8];
    *(uint4*)(orow + 784 + kq * 16)     = *(uint4*)&s[0];
    *(uint4*)(orow + 784 + kq * 16 + 8) = *(uint4*)&s[8];
  } else {
    uint4 z = {0, 0, 0, 0};
#pragma unroll
    for (int q = 0; q < 4; ++q) *(uint4*)(orow + 1568 + q * 8) = z;
  }
}

// Layer 1: bf16 MFMA GEMM, m97 structure: global_load_lds(16B) staging,
// 128x128 tile, BK=64, XOR-swizzled chunks (bank-conflict-free ds_read_b128).
// Epilogue: BN sign + ballot pack + tau fixup list (verified round 5).
__global__ __launch_bounds__(256) void gemm1_mfma_kernel(
    const short* __restrict__ Xhl, const short* __restrict__ Wsd,
    const float* __restrict__ Bv, const float* __restrict__ Gv,
    const float* __restrict__ BEv, const float* __restrict__ Mv,
    const float* __restrict__ Vv,
    uint32_t* __restrict__ bits_out, int* __restrict__ cnt,
    uint32_t* __restrict__ list) {
  __shared__ short Ah[128 * 64];            // 16 KB  [m][k-chunk swizzled]
  __shared__ short Bh[128 * 64];            // 16 KB  [n][k-chunk swizzled]
  __shared__ unsigned short PW16[128 * 8];  // 2 KB

  const int tid = threadIdx.x;
  const int bid = blockIdx.x;
  const int grp = bid >> 10;                // 0..3
  const int rem = bid & 1023;
  const int cb  = (grp << 3) + (rem & 7);   // 0..31
  const int rb  = rem >> 3;                 // 0..127
  const int m0 = rb * 128, n0 = cb * 128;

  const int lane = tid & 63;
  const int w  = tid >> 6;            // wave 0..3
  const int wm = w & 1;               // row-half
  const int wn = w >> 1;              // col-half
  const int l15 = lane & 15;
  const int l4  = lane >> 4;          // 0..3

  f32x4 acc[4][4];
#pragma unroll
  for (int i = 0; i < 4; ++i)
#pragma unroll
    for (int j = 0; j < 4; ++j) acc[i][j] = (f32x4){0.f, 0.f, 0.f, 0.f};

  // staging: wave w covers rows [w*32, w*32+32) of both tiles.
  // lane -> row group (lane>>3), chunk (lane&7) XOR-swizzled by row&7 on the
  // GLOBAL side so LDS slot (row, c) holds global chunk c^(row&7).
  const int srow = lane >> 3;                    // 0..7
  const int schunk = (lane & 7) ^ srow;          // swizzled source chunk
  const char* gA = (const char*)(Xhl + (size_t)(m0 + w * 32) * KP)
                   + (size_t)srow * (KP * 2) + schunk * 16;
  const char* gB = (const char*)(Wsd + (size_t)(n0 + w * 32) * KP)
                   + (size_t)srow * (KP * 2) + schunk * 16;
  short* ldsA = &Ah[(w * 32) * 64];
  short* ldsB = &Bh[(w * 32) * 64];

  for (int s = 0; s < 25; ++s) {         // 25 slabs of BK=64 over KP=1600
#pragma unroll
    for (int rr = 0; rr < 4; ++rr) {
      load16_to_lds(gA + (size_t)rr * 8 * KP * 2, ldsA + rr * 8 * 64);
      load16_to_lds(gB + (size_t)rr * 8 * KP * 2, ldsB + rr * 8 * 64);
    }
    gA += 128;  gB += 128;               // advance 64 bf16
    __syncthreads();                     // drains vmcnt -> LDS valid
#pragma unroll
    for (int h = 0; h < 2; ++h) {        // two K=32 halves
      frag8 af[4], bf[4];
#pragma unroll
      for (int f = 0; f < 4; ++f) {
        const int ma = wm * 64 + f * 16 + l15;
        const int nb = wn * 64 + f * 16 + l15;
        const int ca = ((h * 4 + l4) ^ (l15 & 7)) * 8;
        af[f] = *(const frag8*)&Ah[ma * 64 + ca];
        bf[f] = *(const frag8*)&Bh[nb * 64 + ca];
      }
#pragma unroll
      for (int fm = 0; fm < 4; ++fm)
#pragma unroll
        for (int fn = 0; fn < 4; ++fn)
          acc[fm][fn] = __builtin_amdgcn_mfma_f32_16x16x32_bf16(
              af[fm], bf[fn], acc[fm][fn], 0, 0, 0);
    }
    __syncthreads();
  }

  // ---- epilogue: BN sign + borderline flag + ballot pack (verified R5) ----
#pragma unroll
  for (int fn = 0; fn < 4; ++fn) {
    const int gj = n0 + wn * 64 + fn * 16 + l15;
    const float  bj = Bv[gj];
    const double scale = (double)Gv[gj] / sqrt((double)Vv[gj] + BN_EPS);
    const double mj = (double)Mv[gj], bej = (double)BEv[gj];
    const double thr = (double)TAU * fabs(scale);
#pragma unroll
    for (int fm = 0; fm < 4; ++fm) {
#pragma unroll
      for (int r = 0; r < 4; ++r) {
        const int row_l = wm * 64 + fm * 16 + l4 * 4 + r;
        float hb = acc[fm][fn][r] + bj;            // f32, matches chain epilogue
        double bnd = ((double)hb - mj) * scale + bej;
        unsigned int bit = (bnd >= 0.0) ? 1u : 0u;
        unsigned long long mask = __ballot(bit);
        if (l15 == 0)
          PW16[row_l * 8 + (wn * 4 + fn)] =
              (unsigned short)(mask >> (l4 * 16));
        if (fabs(bnd) < thr) {
          int pos = atomicAdd(cnt, 1);
          if (pos < CAP)
            list[pos] = (uint32_t)((m0 + row_l) * HID + gj);
        }
      }
    }
  }
  __syncthreads();
  for (int t = tid; t < 512; t += 256) {
    int row = t >> 2, wc = t & 3;
    uint32_t word = (uint32_t)PW16[row * 8 + wc * 2] |
                    ((uint32_t)PW16[row * 8 + wc * 2 + 1] << 16);
    bits_out[(size_t)(m0 + row) * KW + (n0 >> 5) + wc] = word;
  }
}

// Recompute flagged layer-1 elements with the reference's EXACT semantics:
// sequential ascending-k single f32 FMA chain, then h + b in f32, then BN.
__global__ __launch_bounds__(256) void fixup_chain_kernel(
    const float* __restrict__ X, const float* __restrict__ W,
    const float* __restrict__ Bv, const float* __restrict__ Gv,
    const float* __restrict__ BEv, const float* __restrict__ Mv,
    const float* __restrict__ Vv,
    uint32_t* __restrict__ bits1, const int* __restrict__ cnt,
    const uint32_t* __restrict__ list) {
  int n = *cnt;
  if (n > CAP) n = CAP;
  for (int idx = blockIdx.x * 256 + threadIdx.x; idx < n;
       idx += gridDim.x * 256) {
    uint32_t code = list[idx];
    int i = code >> 12;
    int j = code & (HID - 1);
    const float* xr = X + (size_t)i * DIN;
    const float* wr = W + (size_t)j * DIN;
    float h = 0.f;
    for (int k = 0; k < DIN; k += 4) {     // strictly ascending k
      float4 xv = *(const float4*)(xr + k);
      float4 wv = *(const float4*)(wr + k);
      h = fmaf(xv.x, (wv.x >= 0.f) ? 1.f : -1.f, h);
      h = fmaf(xv.y, (wv.y >= 0.f) ? 1.f : -1.f, h);
      h = fmaf(xv.z, (wv.z >= 0.f) ? 1.f : -1.f, h);
      h = fmaf(xv.w, (wv.w >= 0.f) ? 1.f : -1.f, h);
    }
    float hb = h + Bv[j];
    double scale = (double)Gv[j] / sqrt((double)Vv[j] + BN_EPS);
    double bnd = ((double)hb - (double)Mv[j]) * scale + (double)BEv[j];
    uint32_t bit = (bnd >= 0.0) ? 1u : 0u;
    uint32_t* wpw = &bits1[(size_t)i * KW + (j >> 5)];
    uint32_t cur = (*wpw >> (j & 31)) & 1u;
    if (cur != bit) atomicXor(wpw, 1u << (j & 31));
  }
}

// Layers 2/3: +-1 x +-1 GEMM via XOR+popcount (exact). BN -> sign bits out.
__global__ __launch_bounds__(256) void bitgemm_kernel(
    const uint32_t* __restrict__ Abits, const uint32_t* __restrict__ Wbits,
    const float* __restrict__ Bv, const float* __restrict__ Gv,
    const float* __restrict__ BEv, const float* __restrict__ Mv,
    const float* __restrict__ Vv, uint32_t* __restrict__ bits_out) {
  __shared__ uint32_t As[16 * 128];
  __shared__ uint32_t Bs[16 * 128];
  __shared__ unsigned int PW[128 * 4];

  const int tid = threadIdx.x;
  const int cb = blockIdx.x & 31, rb = blockIdx.x >> 5;
  const int m0 = rb * 128, n0 = cb * 128;
  const int tx = tid & 15, ty = tid >> 4;

  int acc[8][8];
#pragma unroll
  for (int r = 0; r < 8; ++r)
#pragma unroll
    for (int c = 0; c < 8; ++c) acc[r][c] = 0;

  const int sr = tid >> 1;
  const int sk = (tid & 1) * 8;
  const uint32_t* arow = Abits + (size_t)(m0 + sr) * KW + sk;
  const uint32_t* wrow = Wbits + (size_t)(n0 + sr) * KW + sk;

  for (int w0 = 0; w0 < KW; w0 += 16) {
    uint4 a0 = *(const uint4*)(arow + w0);
    uint4 a1 = *(const uint4*)(arow + w0 + 4);
    uint4 b0 = *(const uint4*)(wrow + w0);
    uint4 b1 = *(const uint4*)(wrow + w0 + 4);
    __syncthreads();
    As[(sk + 0) * 128 + sr] = a0.x;  As[(sk + 1) * 128 + sr] = a0.y;
    As[(sk + 2) * 128 + sr] = a0.z;  As[(sk + 3) * 128 + sr] = a0.w;
    As[(sk + 4) * 128 + sr] = a1.x;  As[(sk + 5) * 128 + sr] = a1.y;
    As[(sk + 6) * 128 + sr] = a1.z;  As[(sk + 7) * 128 + sr] = a1.w;
    Bs[(sk + 0) * 128 + sr] = b0.x;  Bs[(sk + 1) * 128 + sr] = b0.y;
    Bs[(sk + 2) * 128 + sr] = b0.z;  Bs[(sk + 3) * 128 + sr] = b0.w;
    Bs[(sk + 4) * 128 + sr] = b1.x;  Bs[(sk + 5) * 128 + sr] = b1.y;
    Bs[(sk + 6) * 128 + sr] = b1.z;  Bs[(sk + 7) * 128 + sr] = b1.w;
    __syncthreads();
#pragma unroll
    for (int kk = 0; kk < 16; ++kk) {
      uint32_t a[8], b[8];
      *(uint4*)&a[0] = *(const uint4*)&As[kk * 128 + ty * 8];
      *(uint4*)&a[4] = *(const uint4*)&As[kk * 128 + ty * 8 + 4];
      *(uint4*)&b[0] = *(const uint4*)&Bs[kk * 128 + tx * 8];
      *(uint4*)&b[4] = *(const uint4*)&Bs[kk * 128 + tx * 8 + 4];
#pragma unroll
      for (int r = 0; r < 8; ++r)
#pragma unroll
        for (int c = 0; c < 8; ++c)
          acc[r][c] += __popc(a[r] ^ b[c]);
    }
  }

  uint32_t bm[8];
#pragma unroll
  for (int r = 0; r < 8; ++r) bm[r] = 0;
  for (int c = 0; c < 8; ++c) {
    const int j = n0 + tx * 8 + c;
    const double scale = (double)Gv[j] / sqrt((double)Vv[j] + BN_EPS);
    const double mj = (double)Mv[j], bej = (double)BEv[j], bj = (double)Bv[j];
#pragma unroll
    for (int r = 0; r < 8; ++r) {
      double h = (double)(HID - 2 * acc[r][c]) + bj;   // exact integer dot
      double bnd = (h - mj) * scale + bej;
      bm[r] |= (uint32_t)(bnd >= 0.0) << c;
    }
  }
  for (int t = tid; t < 512; t += 256) PW[t] = 0u;
  __syncthreads();
#pragma unroll
  for (int r = 0; r < 8; ++r)
    atomicOr(&PW[(ty * 8 + r) * 4 + (tx >> 2)], bm[r] << (8 * (tx & 3)));
  __syncthreads();
  for (int w = tid; w < 512; w += 256) {
    int row = w >> 2, wc = w & 3;
    bits_out[(size_t)(m0 + row) * KW + (n0 >> 5) + wc] = PW[row * 4 + wc];
  }
}

// Layer 4 (10 outputs) + log_softmax. One wave per batch row.
__global__ __launch_bounds__(256) void final_kernel(
    const uint32_t* __restrict__ xbits, const uint32_t* __restrict__ w4b,
    const float* __restrict__ b4, float* __restrict__ out) {
  __shared__ uint32_t Ws[DOUT * KW];   // 5 KB
  const int tid = threadIdx.x;
  for (int t = tid; t < DOUT * KW; t += 256) Ws[t] = w4b[t];
  __syncthreads();
  const int lane = tid & 63;
  const int i = blockIdx.x * 4 + (tid >> 6);
  const uint32_t x0 = xbits[(size_t)i * KW + lane];
  const uint32_t x1 = xbits[(size_t)i * KW + 64 + lane];
  int cnt[DOUT];
#pragma unroll
  for (int j = 0; j < DOUT; ++j)
    cnt[j] = __popc(x0 ^ Ws[j * KW + lane]) + __popc(x1 ^ Ws[j * KW + 64 + lane]);
#pragma unroll
  for (int j = 0; j < DOUT; ++j)
#pragma unroll
    for (int off = 32; off; off >>= 1) cnt[j] += __shfl_xor(cnt[j], off);
  double logit[DOUT];
  double mx = -1e300;
#pragma unroll
  for (int j = 0; j < DOUT; ++j) {
    logit[j] = (double)(HID - 2 * cnt[j]) + (double)b4[j];
    mx = fmax(mx, logit[j]);
  }
  double s = 0.0;
#pragma unroll
  for (int j = 0; j < DOUT; ++j) s += exp(logit[j] - mx);
  double lse = log(s) + mx;
  if (lane < DOUT)
    out[(size_t)i * DOUT + lane] = (float)(logit[lane] - lse);
}

extern "C" void kernel_launch(void* const* d_in, const int* in_sizes, int n_in,
                              void* d_out, int out_size, void* d_ws, size_t ws_size,
                              hipStream_t stream) {
  const float* x   = (const float*)d_in[0];
  const float* w1  = (const float*)d_in[1];
  const float* b1  = (const float*)d_in[2];
  const float* g1  = (const float*)d_in[3];
  const float* be1 = (const float*)d_in[4];
  const float* m1  = (const float*)d_in[5];
  const float* v1  = (const float*)d_in[6];
  const float* w2  = (const float*)d_in[7];
  const float* b2  = (const float*)d_in[8];
  const float* g2  = (const float*)d_in[9];
  const float* be2 = (const float*)d_in[10];
  const float* m2  = (const float*)d_in[11];
  const float* v2  = (const float*)d_in[12];
  const float* w3  = (const float*)d_in[13];
  const float* b3  = (const float*)d_in[14];
  const float* g3  = (const float*)d_in[15];
  const float* be3 = (const float*)d_in[16];
  const float* m3  = (const float*)d_in[17];
  const float* v3  = (const float*)d_in[18];
  const float* w4  = (const float*)d_in[19];
  const float* b4  = (const float*)d_in[20];

  char* ws = (char*)d_ws;
  uint32_t* bits1 = (uint32_t*)(ws + OFF_BITS1);
  uint32_t* bits2 = (uint32_t*)(ws + OFF_BITS2);
  uint32_t* w2b   = (uint32_t*)(ws + OFF_W2B);
  uint32_t* w3b   = (uint32_t*)(ws + OFF_W3B);
  uint32_t* w4b   = (uint32_t*)(ws + OFF_W4B);
  int*      cnt   = (int*)(ws + OFF_CNT);
  uint32_t* list  = (uint32_t*)(ws + OFF_LIST);
  short*    xhl   = (short*)(ws + OFF_XHL);
  short*    wsd   = (short*)(ws + OFF_WSD);
  float*    out   = (float*)d_out;

  zero_cnt_kernel<<<1, 64, 0, stream>>>(cnt);
  binarize_kernel<<<(HID * KW + 255) / 256, 256, 0, stream>>>(w2, w2b, HID * KW);
  binarize_kernel<<<(HID * KW + 255) / 256, 256, 0, stream>>>(w3, w3b, HID * KW);
  binarize_kernel<<<(DOUT * KW + 255) / 256, 256, 0, stream>>>(w4, w4b, DOUT * KW);
  convert_x_kernel<<<(BATCH * 50) / 256, 256, 0, stream>>>(x, xhl);
  convert_w_kernel<<<(HID * 50) / 256, 256, 0, stream>>>(w1, wsd);

  gemm1_mfma_kernel<<<(BATCH / 128) * (HID / 128), 256, 0, stream>>>(
      xhl, wsd, b1, g1, be1, m1, v1, bits1, cnt, list);
  fixup_chain_kernel<<<512, 256, 0, stream>>>(
      x, w1, b1, g1, be1, m1, v1, bits1, cnt, list);

  bitgemm_kernel<<<(BATCH / 128) * (HID / 128), 256, 0, stream>>>(
      bits1, w2b, b2, g2, be2, m2, v2, bits2);
  bitgemm_kernel<<<(BATCH / 128) * (HID / 128), 256, 0, stream>>>(
      bits2, w3b, b3, g3, be3, m3, v3, bits1);

  final_kernel<<<BATCH / 4, 256, 0, stream>>>(bits1, w4b, b4, out);
}